// Round 6
// baseline (137.028 us; speedup 1.0000x reference)
//
#include <hip/hip_runtime.h>

#define BATCH 256
#define NV    5000
#define NCLS  20000
#define G     4                 // batch rows per block (interleaved by 4 in LDS)
#define NT    1024              // 16 waves/block; 2 blocks/CU -> 32 waves/CU
#define NCH   8                 // clause chunks
#define CCH   (NCLS / NCH)      // 2500
#define NBLK  (NCH * BATCH / G) // 512 blocks = 2 per CU at 80 KB LDS

// Horner over the 3 selector bits; f-deltas precomputed (shared across rows).
__device__ __forceinline__ float eval_c(float f0, float d0, float f2, float d1,
                                        float f4, float d2, float f6, float d3,
                                        float p0, float p1, float p2) {
    float t0 = fmaf(d0, p2, f0);
    float t1 = fmaf(d1, p2, f2);
    float t2 = fmaf(d2, p2, f4);
    float t3 = fmaf(d3, p2, f6);
    float u0 = fmaf(t1 - t0, p1, t0);
    float u1 = fmaf(t3 - t2, p1, t2);
    return fmaf(u1 - u0, p0, u0);
}

// Single dispatch. Block (bg = blk & 63, cs = blk >> 6). Partials -> ws,
// then ticketed last-block does the deterministic fixed-order reduce.
__global__ __launch_bounds__(NT)
void bmn_main(const float* __restrict__ x,
              const int*   __restrict__ vars,
              const float* __restrict__ factors,
              float* __restrict__ partial,
              int*   __restrict__ ticket,
              float* __restrict__ out) {
    __shared__ float xs[NV * G];          // 80 KB: xs[v*4 + g]
    const int bg  = blockIdx.x & (BATCH / G - 1);
    const int cs  = blockIdx.x >> 6;
    const int tid = threadIdx.x;

    const float* xr = x + bg * G * NV;
    for (int i = tid; i < NV; i += NT) {
        float4 v;
        v.x = xr[i];
        v.y = xr[i + NV];
        v.z = xr[i + 2 * NV];
        v.w = xr[i + 3 * NV];
        *reinterpret_cast<float4*>(&xs[i * 4]) = v;   // consecutive b128: conflict-free
    }
    __syncthreads();

    float4 acc = make_float4(0.f, 0.f, 0.f, 0.f);
    const int cbase = cs * CCH;
    const int cend  = cbase + CCH;
    for (int c = cbase + tid; c < cend; c += NT) {
        const int v0 = vars[c * 3 + 0];
        const int v1 = vars[c * 3 + 1];
        const int v2 = vars[c * 3 + 2];
        const float4 fa = *reinterpret_cast<const float4*>(factors + c * 8);
        const float4 fb = *reinterpret_cast<const float4*>(factors + c * 8 + 4);
        const float4 p0 = *reinterpret_cast<const float4*>(&xs[v0 * 4]);
        const float4 p1 = *reinterpret_cast<const float4*>(&xs[v1 * 4]);
        const float4 p2 = *reinterpret_cast<const float4*>(&xs[v2 * 4]);
        const float d0 = fa.y - fa.x, d1 = fa.w - fa.z;
        const float d2 = fb.y - fb.x, d3 = fb.w - fb.z;
        acc.x += eval_c(fa.x, d0, fa.z, d1, fb.x, d2, fb.z, d3, p0.x, p1.x, p2.x);
        acc.y += eval_c(fa.x, d0, fa.z, d1, fb.x, d2, fb.z, d3, p0.y, p1.y, p2.y);
        acc.z += eval_c(fa.x, d0, fa.z, d1, fb.x, d2, fb.z, d3, p0.z, p1.z, p2.z);
        acc.w += eval_c(fa.x, d0, fa.z, d1, fb.x, d2, fb.z, d3, p0.w, p1.w, p2.w);
    }

    // wave reduce (64 lanes)
    for (int off = 32; off; off >>= 1) {
        acc.x += __shfl_down(acc.x, off, 64);
        acc.y += __shfl_down(acc.y, off, 64);
        acc.z += __shfl_down(acc.z, off, 64);
        acc.w += __shfl_down(acc.w, off, 64);
    }
    __shared__ float red[NT / 64][G];
    if ((tid & 63) == 0) {
        const int w = tid >> 6;
        red[w][0] = acc.x; red[w][1] = acc.y; red[w][2] = acc.z; red[w][3] = acc.w;
    }
    __syncthreads();
    if (tid < G) {
        float s = 0.f;
        #pragma unroll
        for (int w = 0; w < NT / 64; ++w) s += red[w][tid];
        partial[cs * BATCH + bg * G + tid] = s;
    }

    // ----- ticketed last-block reduction (no cooperative launch) -----
    __threadfence();                       // release partials to device scope
    __shared__ int lastFlag;
    if (tid == 0)
        lastFlag = (atomicAdd(ticket, 1) == NBLK - 1);
    __syncthreads();
    if (lastFlag) {
        __threadfence();                   // acquire
        if (tid < BATCH) {
            float s = 0.f;
            #pragma unroll
            for (int k = 0; k < NCH; ++k)  // fixed order -> deterministic
                s += __hip_atomic_load(&partial[k * BATCH + tid],
                                       __ATOMIC_RELAXED, __HIP_MEMORY_SCOPE_AGENT);
            out[tid] = s;
        }
    }
}

// Fallback (ws too small): direct write, one block per 4 rows. Correct, slower.
__global__ __launch_bounds__(NT)
void bmn_direct(const float* __restrict__ x,
                const int*   __restrict__ vars,
                const float* __restrict__ factors,
                float* __restrict__ out) {
    __shared__ float xs[NV * G];
    const int bg  = blockIdx.x;
    const int tid = threadIdx.x;
    const float* xr = x + bg * G * NV;
    for (int i = tid; i < NV; i += NT) {
        float4 v;
        v.x = xr[i]; v.y = xr[i + NV]; v.z = xr[i + 2 * NV]; v.w = xr[i + 3 * NV];
        *reinterpret_cast<float4*>(&xs[i * 4]) = v;
    }
    __syncthreads();
    float4 acc = make_float4(0.f, 0.f, 0.f, 0.f);
    for (int c = tid; c < NCLS; c += NT) {
        const int v0 = vars[c * 3 + 0];
        const int v1 = vars[c * 3 + 1];
        const int v2 = vars[c * 3 + 2];
        const float4 fa = *reinterpret_cast<const float4*>(factors + c * 8);
        const float4 fb = *reinterpret_cast<const float4*>(factors + c * 8 + 4);
        const float4 p0 = *reinterpret_cast<const float4*>(&xs[v0 * 4]);
        const float4 p1 = *reinterpret_cast<const float4*>(&xs[v1 * 4]);
        const float4 p2 = *reinterpret_cast<const float4*>(&xs[v2 * 4]);
        const float d0 = fa.y - fa.x, d1 = fa.w - fa.z;
        const float d2 = fb.y - fb.x, d3 = fb.w - fb.z;
        acc.x += eval_c(fa.x, d0, fa.z, d1, fb.x, d2, fb.z, d3, p0.x, p1.x, p2.x);
        acc.y += eval_c(fa.x, d0, fa.z, d1, fb.x, d2, fb.z, d3, p0.y, p1.y, p2.y);
        acc.z += eval_c(fa.x, d0, fa.z, d1, fb.x, d2, fb.z, d3, p0.z, p1.z, p2.z);
        acc.w += eval_c(fa.x, d0, fa.z, d1, fb.x, d2, fb.z, d3, p0.w, p1.w, p2.w);
    }
    for (int off = 32; off; off >>= 1) {
        acc.x += __shfl_down(acc.x, off, 64);
        acc.y += __shfl_down(acc.y, off, 64);
        acc.z += __shfl_down(acc.z, off, 64);
        acc.w += __shfl_down(acc.w, off, 64);
    }
    __shared__ float red[NT / 64][G];
    if ((tid & 63) == 0) {
        const int w = tid >> 6;
        red[w][0] = acc.x; red[w][1] = acc.y; red[w][2] = acc.z; red[w][3] = acc.w;
    }
    __syncthreads();
    if (tid < G) {
        float s = 0.f;
        #pragma unroll
        for (int w = 0; w < NT / 64; ++w) s += red[w][tid];
        out[bg * G + tid] = s;
    }
}

extern "C" void kernel_launch(void* const* d_in, const int* in_sizes, int n_in,
                              void* d_out, int out_size, void* d_ws, size_t ws_size,
                              hipStream_t stream) {
    const float* x       = (const float*)d_in[0];
    // d_in[1] = binary_combinations (bit order hard-coded; verified rounds 1-5)
    const int*   vars    = (const int*)d_in[2];
    const float* factors = (const float*)d_in[3];
    float* out = (float*)d_out;

    const size_t pp_bytes = (size_t)(NCH * BATCH) * sizeof(float);   // 8 KB
    if (ws_size >= pp_bytes + sizeof(int)) {
        float* partial = (float*)d_ws;
        int*   ticket  = (int*)((char*)d_ws + pp_bytes);
        hipMemsetAsync(ticket, 0, sizeof(int), stream);              // graph-capturable
        bmn_main<<<dim3(NBLK), NT, 0, stream>>>(x, vars, factors, partial, ticket, out);
    } else {
        bmn_direct<<<dim3(BATCH / G), NT, 0, stream>>>(x, vars, factors, out);
    }
}

// Round 7
// 16.542 us; speedup vs baseline: 8.2838x; 8.2838x over previous
//
#include <hip/hip_runtime.h>

#define BATCH 256
#define NV    5000
#define NCLS  20000
#define G     4                 // batch rows per block (interleaved by 4 in LDS)
#define NT    512               // 8 waves/block; 2 blocks/CU -> 16 waves/CU
#define NCH   8                 // clause chunks
#define CCH   (NCLS / NCH)      // 2500
#define NBLK  (NCH * BATCH / G) // 512 blocks = 2/CU at 80 KB LDS
#define KMAX  5                 // ceil(CCH / NT)

// Horner over the 3 selector bits; f-deltas shared across the 4 rows.
__device__ __forceinline__ float eval_c(float f0, float d0, float f2, float d1,
                                        float f4, float d2, float f6, float d3,
                                        float p0, float p1, float p2) {
    float t0 = fmaf(d0, p2, f0);
    float t1 = fmaf(d1, p2, f2);
    float t2 = fmaf(d2, p2, f4);
    float t3 = fmaf(d3, p2, f6);
    float u0 = fmaf(t1 - t0, p1, t0);
    float u1 = fmaf(t3 - t2, p1, t2);
    return fmaf(u1 - u0, p0, u0);
}

// Single dispatch. Block (bg = blk & 63, cs = blk >> 6). Each block owns
// 4 batch rows x 2500 clauses; results accumulated into out via atomicAdd
// (out zeroed by a memset node in the same stream).
__global__ __launch_bounds__(NT, 4)   // cap VGPR<=128: R6 showed the default chokes
void bmn_main(const float* __restrict__ x,
              const int*   __restrict__ vars,
              const float* __restrict__ factors,
              float* __restrict__ out) {
    __shared__ float xs[NV * G];          // 80 KB: xs[v*4 + g]
    const int bg  = blockIdx.x & (BATCH / G - 1);
    const int cs  = blockIdx.x >> 6;
    const int tid = threadIdx.x;
    const int cbase = cs * CCH;
    const int c0    = cbase + tid;

    // ---- batched clause loads: issue ALL long-latency loads up front ----
    int   va[KMAX], vb[KMAX], vc[KMAX];
    float4 FA[KMAX], FB[KMAX];
    #pragma unroll
    for (int k = 0; k < KMAX; ++k) {
        int c = c0 + k * NT;
        if (k == KMAX - 1 && c >= cbase + CCH) c = c0;   // dup-load; masked below
        va[k] = vars[c * 3 + 0];
        vb[k] = vars[c * 3 + 1];
        vc[k] = vars[c * 3 + 2];
        FA[k] = *reinterpret_cast<const float4*>(factors + c * 8);
        FB[k] = *reinterpret_cast<const float4*>(factors + c * 8 + 4);
    }
    {   // tail mask: zero factors -> zero contribution (eval is linear in f)
        const float m = (c0 + (KMAX - 1) * NT < cbase + CCH) ? 1.f : 0.f;
        FA[KMAX - 1].x *= m; FA[KMAX - 1].y *= m; FA[KMAX - 1].z *= m; FA[KMAX - 1].w *= m;
        FB[KMAX - 1].x *= m; FB[KMAX - 1].y *= m; FB[KMAX - 1].z *= m; FB[KMAX - 1].w *= m;
    }

    // ---- stage 4 x-rows into LDS (their latency overlaps the loads above) ----
    const float* xr = x + bg * G * NV;
    for (int i = tid; i < NV; i += NT) {
        float4 v;
        v.x = xr[i];
        v.y = xr[i + NV];
        v.z = xr[i + 2 * NV];
        v.w = xr[i + 3 * NV];
        *reinterpret_cast<float4*>(&xs[i * 4]) = v;   // consecutive b128: conflict-free
    }
    __syncthreads();

    // ---- fully unrolled eval: 15 independent b128 gathers, then math ----
    const float4* xs4 = reinterpret_cast<const float4*>(xs);
    float4 acc = make_float4(0.f, 0.f, 0.f, 0.f);
    #pragma unroll
    for (int k = 0; k < KMAX; ++k) {
        const float4 p0 = xs4[va[k]];
        const float4 p1 = xs4[vb[k]];
        const float4 p2 = xs4[vc[k]];
        const float d0 = FA[k].y - FA[k].x, d1 = FA[k].w - FA[k].z;
        const float d2 = FB[k].y - FB[k].x, d3 = FB[k].w - FB[k].z;
        acc.x += eval_c(FA[k].x, d0, FA[k].z, d1, FB[k].x, d2, FB[k].z, d3, p0.x, p1.x, p2.x);
        acc.y += eval_c(FA[k].x, d0, FA[k].z, d1, FB[k].x, d2, FB[k].z, d3, p0.y, p1.y, p2.y);
        acc.z += eval_c(FA[k].x, d0, FA[k].z, d1, FB[k].x, d2, FB[k].z, d3, p0.z, p1.z, p2.z);
        acc.w += eval_c(FA[k].x, d0, FA[k].z, d1, FB[k].x, d2, FB[k].z, d3, p0.w, p1.w, p2.w);
    }

    // ---- block reduce: wave shuffle, then cross-wave via LDS ----
    for (int off = 32; off; off >>= 1) {
        acc.x += __shfl_down(acc.x, off, 64);
        acc.y += __shfl_down(acc.y, off, 64);
        acc.z += __shfl_down(acc.z, off, 64);
        acc.w += __shfl_down(acc.w, off, 64);
    }
    __shared__ float red[NT / 64][G];
    if ((tid & 63) == 0) {
        const int w = tid >> 6;
        red[w][0] = acc.x; red[w][1] = acc.y; red[w][2] = acc.z; red[w][3] = acc.w;
    }
    __syncthreads();
    if (tid < G) {
        float s = 0.f;
        #pragma unroll
        for (int w = 0; w < NT / 64; ++w) s += red[w][tid];
        atomicAdd(&out[bg * G + tid], s);   // 8 contributions per output row
    }
}

extern "C" void kernel_launch(void* const* d_in, const int* in_sizes, int n_in,
                              void* d_out, int out_size, void* d_ws, size_t ws_size,
                              hipStream_t stream) {
    const float* x       = (const float*)d_in[0];
    // d_in[1] = binary_combinations (bit order hard-coded; verified rounds 1-6)
    const int*   vars    = (const int*)d_in[2];
    const float* factors = (const float*)d_in[3];
    float* out = (float*)d_out;

    hipMemsetAsync(out, 0, (size_t)BATCH * sizeof(float), stream);  // capturable node
    bmn_main<<<dim3(NBLK), NT, 0, stream>>>(x, vars, factors, out);
}

// Round 8
// 13.413 us; speedup vs baseline: 10.2162x; 1.2333x over previous
//
#include <hip/hip_runtime.h>

#define BATCH 256
#define NV    5000
#define NCLS  20000
#define G     2           // batch rows per block (interleaved by 2 in LDS, 40 KB)
#define NT    512         // 8 waves/block; 40 KB LDS -> 4 blocks/CU = 32 waves/CU
#define NCH   8           // clause chunks; grid = 128 x 8 = 1024 blocks (4x oversub)

// Horner over the 3 selector bits; f-deltas precomputed (shared across rows).
__device__ __forceinline__ float eval_c(float f0, float d0, float f2, float d1,
                                        float f4, float d2, float f6, float d3,
                                        float p0, float p1, float p2) {
    float t0 = fmaf(d0, p2, f0);
    float t1 = fmaf(d1, p2, f2);
    float t2 = fmaf(d2, p2, f4);
    float t3 = fmaf(d3, p2, f6);
    float u0 = fmaf(t1 - t0, p1, t0);
    float u1 = fmaf(t3 - t2, p1, t2);
    return fmaf(u1 - u0, p0, u0);
}

// Block (bg, cs): batch rows [bg*G, bg*G+G), clause chunk cs of size cchunk.
// Partial sums -> outbuf[cs*BATCH + b].  (R2-proven body; only G changed.)
__global__ __launch_bounds__(NT, 8)   // cap VGPR<=64 so 8 waves/SIMD are resident
void bmn_main(const float* __restrict__ x,
              const int*   __restrict__ vars,
              const float* __restrict__ factors,
              float* __restrict__ outbuf,
              int cchunk) {
    __shared__ float xs[NV * G];          // 40 KB: xs[v*2 + g]
    const int bg  = blockIdx.x;
    const int cs  = blockIdx.y;
    const int tid = threadIdx.x;

    const float* row0 = x + (bg * G + 0) * NV;
    const float* row1 = x + (bg * G + 1) * NV;
    for (int i = tid; i < NV; i += NT) {
        float2 v2 = make_float2(row0[i], row1[i]);
        *reinterpret_cast<float2*>(&xs[i * 2]) = v2;   // consecutive b64: conflict-free
    }
    __syncthreads();

    float2 acc = make_float2(0.f, 0.f);
    const float2* xs2 = reinterpret_cast<const float2*>(xs);
    const int cbase = cs * cchunk;
    const int cend  = cbase + cchunk;
    for (int c = cbase + tid; c < cend; c += NT) {
        const int v0 = vars[c * 3 + 0];
        const int v1 = vars[c * 3 + 1];
        const int v2 = vars[c * 3 + 2];
        const float4 fa = *reinterpret_cast<const float4*>(factors + c * 8);
        const float4 fb = *reinterpret_cast<const float4*>(factors + c * 8 + 4);
        const float2 p0 = xs2[v0];        // one ds_read_b64 serves both rows
        const float2 p1 = xs2[v1];
        const float2 p2 = xs2[v2];
        const float d0 = fa.y - fa.x, d1 = fa.w - fa.z;
        const float d2 = fb.y - fb.x, d3 = fb.w - fb.z;
        acc.x += eval_c(fa.x, d0, fa.z, d1, fb.x, d2, fb.z, d3, p0.x, p1.x, p2.x);
        acc.y += eval_c(fa.x, d0, fa.z, d1, fb.x, d2, fb.z, d3, p0.y, p1.y, p2.y);
    }

    // wave reduce (64 lanes)
    for (int off = 32; off; off >>= 1) {
        acc.x += __shfl_down(acc.x, off, 64);
        acc.y += __shfl_down(acc.y, off, 64);
    }
    __shared__ float red[NT / 64][G];
    if ((tid & 63) == 0) {
        const int w = tid >> 6;
        red[w][0] = acc.x; red[w][1] = acc.y;
    }
    __syncthreads();
    if (tid < G) {
        float s = 0.f;
        #pragma unroll
        for (int w = 0; w < NT / 64; ++w) s += red[w][tid];
        outbuf[cs * BATCH + bg * G + tid] = s;
    }
}

__global__ __launch_bounds__(BATCH)
void bmn_reduce(const float* __restrict__ ws, float* __restrict__ out) {
    const int b = threadIdx.x;            // coalesced in b
    float s = 0.f;
    #pragma unroll
    for (int cs = 0; cs < NCH; ++cs) s += ws[cs * BATCH + b];
    out[b] = s;
}

extern "C" void kernel_launch(void* const* d_in, const int* in_sizes, int n_in,
                              void* d_out, int out_size, void* d_ws, size_t ws_size,
                              hipStream_t stream) {
    const float* x       = (const float*)d_in[0];
    // d_in[1] = binary_combinations (bit order hard-coded; verified rounds 1-7)
    const int*   vars    = (const int*)d_in[2];
    const float* factors = (const float*)d_in[3];
    float* out = (float*)d_out;

    if (ws_size >= (size_t)(NCH * BATCH) * sizeof(float)) {
        float* ws = (float*)d_ws;
        bmn_main<<<dim3(BATCH / G, NCH), NT, 0, stream>>>(x, vars, factors, ws, NCLS / NCH);
        bmn_reduce<<<1, BATCH, 0, stream>>>(ws, out);
    } else {
        // fallback: single chunk writes final sums directly (correct, slower)
        bmn_main<<<dim3(BATCH / G, 1), NT, 0, stream>>>(x, vars, factors, out, NCLS);
    }
}